// Round 11
// baseline (262.927 us; speedup 1.0000x reference)
//
#include <hip/hip_runtime.h>

#define EPS   0.01f
#define ALPHA 0.1f
#define H     60

typedef float f32x2 __attribute__((ext_vector_type(2)));

__device__ __forceinline__ float softplusf(float x) {
    // stable: max(x,0) + log1p(exp(-|x|))
    float e = __expf(-fabsf(x));
    return fmaxf(x, 0.f) + __logf(1.f + e);
}

// ---- setup: g0 scalar only ----
__global__ void g0_kernel(const float* __restrict__ W2, const float* __restrict__ b1,
                          const float* __restrict__ b2, const float* __restrict__ W3,
                          const float* __restrict__ b3, float* __restrict__ g0_out) {
    if (threadIdx.x != 0 || blockIdx.x != 0) return;
    float h1[H];
    for (int k = 0; k < H; ++k) h1[k] = softplusf(b1[k]);
    float z3 = b3[0];
    for (int j = 0; j < H; ++j) {
        float acc = b2[j];
        for (int k = 0; k < H; ++k) acc = fmaf(W2[j * H + k], h1[k], acc);
        z3 = fmaf(W3[j], softplusf(acc), z3);
    }
    g0_out[0] = softplusf(z3);
}

// ---- main: one row per thread; h1/G as float2 k-pairs; PLAIN C vector math.
// Round-10 lesson: inline-asm "v" constraints on AGPR-resident arrays force
// v_accvgpr_read/write around every op (~2x instruction bloat). Plain C lets
// the compiler either keep state in arch VGPRs (waves_per_eu(2,2) gives it a
// 256-reg budget) or access unified-file regs directly — no pinned copies. ----
__global__ __launch_bounds__(256)
__attribute__((amdgpu_waves_per_eu(2, 2)))
void sdnn_kernel(
    const float* __restrict__ X,   const float* __restrict__ Wf,
    const float* __restrict__ W1,  const float* __restrict__ b1,
    const float* __restrict__ W2,  const float* __restrict__ b2,
    const float* __restrict__ W3,  const float* __restrict__ b3,
    const float* __restrict__ Wim2,const float* __restrict__ Wim3,
    const float* __restrict__ g0p, float* __restrict__ out, int B)
{
    const int row = blockIdx.x * 256 + threadIdx.x;
    if (row >= B) return;

    const float2 xv = ((const float2*)X)[row];
    const float x0 = xv.x, x1 = xv.y;

    // layer 1: h1 pairs (f32)
    f32x2 h1p[H / 2];
#pragma unroll
    for (int p = 0; p < H / 2; ++p) {
        const float za = fmaf(W1[4 * p],     x0, fmaf(W1[4 * p + 1], x1, b1[2 * p]));
        const float zb = fmaf(W1[4 * p + 2], x0, fmaf(W1[4 * p + 3], x1, b1[2 * p + 1]));
        h1p[p].x = softplusf(za);
        h1p[p].y = softplusf(zb);
    }

    // G pairs (f32)
    f32x2 Gp[H / 2];
#pragma unroll
    for (int p = 0; p < H / 2; ++p) Gp[p] = (f32x2){0.f, 0.f};

    const float wi30 = Wim3[0], wi31 = Wim3[1];
    float z3 = fmaf(wi30, x0, fmaf(wi31, x1, b3[0]));
    float gim0 = 0.f, gim1 = 0.f;

    const f32x2* __restrict__ W2p = (const f32x2*)W2;   // row j = pairs [j*30 .. j*30+29]

    for (int j = 0; j < H; ++j) {
        const f32x2* __restrict__ wrow = &W2p[j * (H / 2)];
        // z2_j = W2[j,:]·h1 : pairs 0..27 in 4-acc loop, tail pairs 28,29 explicit
        f32x2 a0 = {0.f, 0.f}, a1 = {0.f, 0.f}, a2 = {0.f, 0.f}, a3 = {0.f, 0.f};
#pragma unroll
        for (int p = 0; p < 28; p += 4) {
            a0 += wrow[p + 0] * h1p[p + 0];
            a1 += wrow[p + 1] * h1p[p + 1];
            a2 += wrow[p + 2] * h1p[p + 2];
            a3 += wrow[p + 3] * h1p[p + 3];
        }
        a0 += wrow[28] * h1p[28];
        a1 += wrow[29] * h1p[29];
        const float z2 = ((a0.x + a0.y) + (a1.x + a1.y)) + ((a2.x + a2.y) + (a3.x + a3.y))
                       + fmaf(Wim2[2 * j], x0, fmaf(Wim2[2 * j + 1], x1, b2[j]));
        const float e2 = __expf(-fabsf(z2));
        const float h2 = fmaxf(z2, 0.f) + __logf(1.f + e2);
        const float w3j = W3[j];
        z3 = fmaf(w3j, h2, z3);
        const float tj = w3j * (1.f - __expf(-h2));   // W3[j]*sigmoid(z2_j)
        gim0 = fmaf(tj, Wim2[2 * j],     gim0);
        gim1 = fmaf(tj, Wim2[2 * j + 1], gim1);

        const f32x2 t2 = {tj, tj};
#pragma unroll
        for (int p = 0; p < H / 2; ++p) Gp[p] += wrow[p] * t2;   // G += W2[j,:] * tj
    }

    // backward finish: u1_k = G_k * sigmoid(z1_k); sigmoid = 1-exp(-h1)
    float q0 = 0.f, q1 = 0.f;
#pragma unroll
    for (int p = 0; p < H / 2; ++p) {
        const float ua = Gp[p].x * (1.f - __expf(-h1p[p].x));
        const float ub = Gp[p].y * (1.f - __expf(-h1p[p].y));
        q0 = fmaf(ua, W1[4 * p],     fmaf(ub, W1[4 * p + 2], q0));
        q1 = fmaf(ua, W1[4 * p + 1], fmaf(ub, W1[4 * p + 3], q1));
    }

    const float g0 = g0p[0];
    const float g  = softplusf(z3);
    const float u3 = (g > g0) ? (1.f - __expf(-g)) : 0.f;

    const float dV0 = fmaf(2.f * EPS, x0, u3 * (wi30 + gim0 + q0));
    const float dV1 = fmaf(2.f * EPS, x1, u3 * (wi31 + gim1 + q1));

    const float V  = fmaxf(g - g0, 0.f) + EPS * fmaf(x0, x0, x1 * x1);
    const float f0 = fmaf(Wf[0], x0, Wf[1] * x1);
    const float f1 = fmaf(Wf[2], x0, Wf[3] * x1);
    const float stab = fmaf(ALPHA, V, fmaf(dV0, f0, dV1 * f1));
    const float s    = __fdividef(fmaxf(stab, 0.f), fmaf(dV0, dV0, dV1 * dV1));

    float2 o;
    o.x = f0 - dV0 * s;
    o.y = f1 - dV1 * s;
    ((float2*)out)[row] = o;
}

extern "C" void kernel_launch(void* const* d_in, const int* in_sizes, int n_in,
                              void* d_out, int out_size, void* d_ws, size_t ws_size,
                              hipStream_t stream) {
    const float* X    = (const float*)d_in[0];
    const float* Wf   = (const float*)d_in[1];
    const float* W1   = (const float*)d_in[2];
    const float* b1   = (const float*)d_in[3];
    const float* W2   = (const float*)d_in[4];
    const float* b2   = (const float*)d_in[5];
    const float* W3   = (const float*)d_in[6];
    const float* b3   = (const float*)d_in[7];
    const float* Wim2 = (const float*)d_in[8];
    const float* Wim3 = (const float*)d_in[9];
    float* out = (float*)d_out;
    float* wsf = (float*)d_ws;

    const int B = in_sizes[0] / 2;
    const int nblk = (B + 255) / 256;

    hipLaunchKernelGGL(g0_kernel, dim3(1), dim3(64), 0, stream,
                       W2, b1, b2, W3, b3, wsf);
    hipLaunchKernelGGL(sdnn_kernel, dim3(nblk), dim3(256), 0, stream,
                       X, Wf, W1, b1, W2, b2, W3, b3, Wim2, Wim3, wsf, out, B);
}